// Round 8
// baseline (2653.038 us; speedup 1.0000x reference)
//
#include <hip/hip_runtime.h>

#define N_NODES 50000
#define N_EDGES 800000
#define N_GRAPHS 256
#define N_LAYERS 3
#define DIM 300
#define NFEAT 128
#define EFEAT 16
#define OUTD 128
#define BN_EPS 1e-5f

typedef __attribute__((ext_vector_type(8))) short bfrag8;   // 8 bf16 = 4 VGPR (MFMA A/B operand)
typedef __attribute__((ext_vector_type(4))) float facc4;    // MFMA C/D
typedef __attribute__((ext_vector_type(4))) unsigned short us4;
typedef __attribute__((ext_vector_type(8))) unsigned short us8;

// ---------------- bf16 helpers (RNE) + hi/lo split ----------------
__device__ __forceinline__ unsigned short f2bf(float f) {
    unsigned u = __float_as_uint(f);
    unsigned r = ((u >> 16) & 1u) + 0x7fffu;
    return (unsigned short)((u + r) >> 16);
}
__device__ __forceinline__ float bf2f(unsigned short h) {
    return __uint_as_float(((unsigned)h) << 16);
}
__device__ __forceinline__ void split2(float v, unsigned short& h, unsigned short& l) {
    h = f2bf(v);
    l = f2bf(v - bf2f(h));
}
__device__ __forceinline__ void split2v(float4 v, us4& h, us4& l) {
    unsigned short a, b;
    split2(v.x, a, b); h.x = a; l.x = b;
    split2(v.y, a, b); h.y = a; l.y = b;
    split2(v.z, a, b); h.z = a; l.z = b;
    split2(v.w, a, b); h.w = a; l.w = b;
}

// async global->LDS, 16B per lane. LDS dest = uniform base + lane*16 (HW rule).
__device__ __forceinline__ void load_lds16(const void* gsrc, void* ldsdst) {
    __builtin_amdgcn_global_load_lds(
        (const __attribute__((address_space(1))) unsigned int*)gsrc,
        (__attribute__((address_space(3))) unsigned int*)ldsdst,
        16, 0, 0);
}

#define MFMA16(a, b, c) __builtin_amdgcn_mfma_f32_16x16x32_bf16(a, b, c, 0, 0, 0)

// ---------------------------------------------------------------------------
// fp32 -> bf16 (hi only), vectorized
// ---------------------------------------------------------------------------
__global__ __launch_bounds__(256) void tobf4(
    const float* __restrict__ x, unsigned short* __restrict__ H, int n4)
{
    int i = blockIdx.x * 256 + threadIdx.x;
    if (i >= n4) return;
    float4 v = ((const float4*)x)[i];
    us4 h;
    h.x = f2bf(v.x); h.y = f2bf(v.y); h.z = f2bf(v.z); h.w = f2bf(v.w);
    ((us4*)H)[i] = h;
}

// hn [N][300] fp32 -> hnb [N][304] bf16 (pad zero)
__global__ __launch_bounds__(256) void tobf_pad(
    const float* __restrict__ hn, unsigned short* __restrict__ hnb)
{
    int idx = blockIdx.x * 256 + threadIdx.x;
    if (idx >= N_NODES * 304) return;
    int n = idx / 304;
    int d = idx - n * 304;
    hnb[idx] = (d < DIM) ? f2bf(hn[(size_t)n * DIM + d]) : (unsigned short)0;
}

// ---------------------------------------------------------------------------
// weight conversion: W fp32 [K][N] -> transposed padded hi/lo planes [Np][Kp]
// ---------------------------------------------------------------------------
__global__ __launch_bounds__(256) void conv_wt(
    const float* __restrict__ W, unsigned short* __restrict__ H,
    unsigned short* __restrict__ L, int K, int N, int Kp, int Np)
{
    int idx = blockIdx.x * 256 + threadIdx.x;
    if (idx >= Np * Kp) return;
    int n = idx / Kp;
    int k = idx - n * Kp;
    float v = (n < N && k < K) ? W[(size_t)k * N + n] : 0.f;
    unsigned short h, l;
    split2(v, h, l);
    H[idx] = h;
    L[idx] = l;
}

// ---------------------------------------------------------------------------
// bf16 MFMA GEMM: A plain bf16 [M][Kp]; B transposed hi/lo planes [Np][Kp].
// acc = Ah*Bh + Ah*Bl (2 MFMA/tile). Block 128x128, BK=32, 4 waves 2x2.
// LDS 24KB: A 8KB | Bh 8KB | Bl 8KB. Optional column-stat epilogue (BN).
// ---------------------------------------------------------------------------
__global__ __launch_bounds__(256, 2) void gemm_pp(
    const unsigned short* __restrict__ Ah,
    const unsigned short* __restrict__ Bth, const unsigned short* __restrict__ Btl,
    const float* __restrict__ bias, float* __restrict__ C,
    int M, int N, int Kp, float* __restrict__ stats)
{
    __shared__ unsigned short lds[12288];   // 24 KB
    const int tid = threadIdx.x;
    const int lane = tid & 63;
    const int w = tid >> 6;
    const int m0 = blockIdx.x * 128;
    const int n0 = blockIdx.y * 128;
    const int wm = (w & 1) * 64;
    const int wn = (w >> 1) * 64;

    const int srow = lane >> 2;
    const int scol = (lane & 3) * 8;

    const unsigned short* gp[6];
    unsigned loff[6];
#pragma unroll
    for (int i = 0; i < 6; ++i) {
        int c = w * 6 + i;
        const unsigned short* pl = (c < 8) ? Ah : (c < 16) ? Bth : Btl;
        int rowg;
        if (c < 8) {
            rowg = m0 + (c & 7) * 16 + srow;
            rowg = min(rowg, M - 1);
        } else {
            rowg = n0 + (c & 7) * 16 + srow;
        }
        gp[i] = pl + (size_t)rowg * Kp + scol;
        loff[i] = c * 512;
    }

    facc4 acc[4][4];
    facc4 zero = {0.f, 0.f, 0.f, 0.f};
#pragma unroll
    for (int i = 0; i < 4; ++i)
#pragma unroll
        for (int j = 0; j < 4; ++j) acc[i][j] = zero;

    const int fr = lane & 15;
    const int fq = (lane >> 4) * 8;

    for (int k0 = 0; k0 < Kp; k0 += 32) {
#pragma unroll
        for (int i = 0; i < 6; ++i) {
            load_lds16(gp[i], &lds[loff[i]]);
            gp[i] += 32;
        }
        __syncthreads();

        bfrag8 ah[4], bh[4], bl[4];
#pragma unroll
        for (int t = 0; t < 4; ++t) {
            int ar = wm + t * 16 + fr;
            ah[t] = *(const bfrag8*)&lds[ar * 32 + fq];
            int br = wn + t * 16 + fr;
            bh[t] = *(const bfrag8*)&lds[4096 + br * 32 + fq];
            bl[t] = *(const bfrag8*)&lds[8192 + br * 32 + fq];
        }
#pragma unroll
        for (int i = 0; i < 4; ++i)
#pragma unroll
            for (int j = 0; j < 4; ++j) {
                acc[i][j] = MFMA16(ah[i], bh[j], acc[i][j]);
                acc[i][j] = MFMA16(ah[i], bl[j], acc[i][j]);
            }
        __syncthreads();
    }

    // epilogue: C/D layout col=lane&15, row=(lane>>4)*4+reg
#pragma unroll
    for (int i = 0; i < 4; ++i)
#pragma unroll
        for (int j = 0; j < 4; ++j) {
            int col = n0 + wn + j * 16 + (lane & 15);
            if (col >= N) continue;
            float bv = bias[col];
#pragma unroll
            for (int r = 0; r < 4; ++r) {
                int row = m0 + wm + i * 16 + (lane >> 4) * 4 + r;
                if (row < M)
                    C[(size_t)row * N + col] = acc[i][j][r] + bv;
            }
        }

    if (stats != nullptr) {
#pragma unroll
        for (int j = 0; j < 4; ++j) {
            int col = n0 + wn + j * 16 + (lane & 15);
            float cs = 0.f, cq = 0.f;
            if (col < N) {
                float bv = bias[col];
#pragma unroll
                for (int i = 0; i < 4; ++i)
#pragma unroll
                    for (int r = 0; r < 4; ++r) {
                        int row = m0 + wm + i * 16 + (lane >> 4) * 4 + r;
                        if (row < M) {
                            float y = acc[i][j][r] + bv;
                            cs += y;
                            cq = fmaf(y, y, cq);
                        }
                    }
            }
            cs += __shfl_xor(cs, 16, 64); cq += __shfl_xor(cq, 16, 64);
            cs += __shfl_xor(cs, 32, 64); cq += __shfl_xor(cq, 32, 64);
            if ((lane >> 4) == 0 && col < N) {
                atomicAdd(&stats[col], cs);
                atomicAdd(&stats[N + col], cq);
            }
        }
    }
}

// ---------------------------------------------------------------------------
// Split-bf16 MFMA GEMM, A fp32 with fused BN-affine+ReLU applied during
// staging, split to hi/lo planes (3 MFMA: hh, hl, lh — recovers A precision).
// LDS 32KB: Ah|Al|Bh|Bl. Column-stat epilogue for BN2.
// ---------------------------------------------------------------------------
__global__ __launch_bounds__(256, 2) void gemm_af(
    const float* __restrict__ A, const unsigned short* __restrict__ Bth,
    const unsigned short* __restrict__ Btl, const float* __restrict__ bias,
    float* __restrict__ C, int M, int N, int K, int Kp,
    const float* __restrict__ abn, float* __restrict__ stats)
{
    __shared__ unsigned short lds[16384];   // Ah 8K | Al 8K | Bh 8K | Bl 8K
    const int tid = threadIdx.x;
    const int lane = tid & 63;
    const int w = tid >> 6;
    const int m0 = blockIdx.x * 128;
    const int n0 = blockIdx.y * 128;
    const int wm = (w & 1) * 64;
    const int wn = (w >> 1) * 64;

    const int srow = lane >> 2;
    const int scol = (lane & 3) * 8;

    const unsigned short* gpb[4];
    unsigned loffb[4];
#pragma unroll
    for (int i = 0; i < 4; ++i) {
        int c = w * 4 + i;
        const unsigned short* pl = (c < 8) ? Bth : Btl;
        int rowg = n0 + (c & 7) * 16 + srow;
        gpb[i] = pl + (size_t)rowg * Kp + scol;
        loffb[i] = 8192 + c * 512;
    }

    facc4 acc[4][4];
    facc4 zero = {0.f, 0.f, 0.f, 0.f};
#pragma unroll
    for (int i = 0; i < 4; ++i)
#pragma unroll
        for (int j = 0; j < 4; ++j) acc[i][j] = zero;

    const int fr = lane & 15;
    const int fq = (lane >> 4) * 8;

    for (int k0 = 0; k0 < Kp; k0 += 32) {
#pragma unroll
        for (int i = 0; i < 4; ++i) {
            load_lds16(gpb[i], &lds[loffb[i]]);
            gpb[i] += 32;
        }
        // A fp32 -> BN affine + relu -> split hi/lo bf16 into LDS
#pragma unroll
        for (int i = 0; i < 4; ++i) {
            int idx = tid + i * 256;
            int row = idx >> 3;
            int q4 = idx & 7;
            int rg = min(m0 + row, M - 1);
            int kk = k0 + q4 * 4;
            float4 v;
            if (kk < K) {
                v = *(const float4*)&A[(size_t)rg * K + kk];
                float4 sa = *(const float4*)&abn[kk];
                float4 sb = *(const float4*)&abn[K + kk];
                v.x = fmaxf(fmaf(v.x, sa.x, sb.x), 0.f);
                v.y = fmaxf(fmaf(v.y, sa.y, sb.y), 0.f);
                v.z = fmaxf(fmaf(v.z, sa.z, sb.z), 0.f);
                v.w = fmaxf(fmaf(v.w, sa.w, sb.w), 0.f);
            } else {
                v.x = 0.f; v.y = 0.f; v.z = 0.f; v.w = 0.f;
            }
            us4 h, l;
            split2v(v, h, l);
            *(us4*)&lds[row * 32 + q4 * 4] = h;
            *(us4*)&lds[4096 + row * 32 + q4 * 4] = l;
        }
        __syncthreads();

        bfrag8 ah[4], al[4], bh[4], bl[4];
#pragma unroll
        for (int t = 0; t < 4; ++t) {
            int ar = wm + t * 16 + fr;
            ah[t] = *(const bfrag8*)&lds[ar * 32 + fq];
            al[t] = *(const bfrag8*)&lds[4096 + ar * 32 + fq];
            int br = wn + t * 16 + fr;
            bh[t] = *(const bfrag8*)&lds[8192 + br * 32 + fq];
            bl[t] = *(const bfrag8*)&lds[12288 + br * 32 + fq];
        }
#pragma unroll
        for (int i = 0; i < 4; ++i)
#pragma unroll
            for (int j = 0; j < 4; ++j) {
                acc[i][j] = MFMA16(ah[i], bh[j], acc[i][j]);
                acc[i][j] = MFMA16(ah[i], bl[j], acc[i][j]);
                acc[i][j] = MFMA16(al[i], bh[j], acc[i][j]);
            }
        __syncthreads();
    }

#pragma unroll
    for (int i = 0; i < 4; ++i)
#pragma unroll
        for (int j = 0; j < 4; ++j) {
            int col = n0 + wn + j * 16 + (lane & 15);
            if (col >= N) continue;
            float bv = bias[col];
#pragma unroll
            for (int r = 0; r < 4; ++r) {
                int row = m0 + wm + i * 16 + (lane >> 4) * 4 + r;
                if (row < M)
                    C[(size_t)row * N + col] = acc[i][j][r] + bv;
            }
        }

    if (stats != nullptr) {
#pragma unroll
        for (int j = 0; j < 4; ++j) {
            int col = n0 + wn + j * 16 + (lane & 15);
            float cs = 0.f, cq = 0.f;
            if (col < N) {
                float bv = bias[col];
#pragma unroll
                for (int i = 0; i < 4; ++i)
#pragma unroll
                    for (int r = 0; r < 4; ++r) {
                        int row = m0 + wm + i * 16 + (lane >> 4) * 4 + r;
                        if (row < M) {
                            float y = acc[i][j][r] + bv;
                            cs += y;
                            cq = fmaf(y, y, cq);
                        }
                    }
            }
            cs += __shfl_xor(cs, 16, 64); cq += __shfl_xor(cq, 16, 64);
            cs += __shfl_xor(cs, 32, 64); cq += __shfl_xor(cq, 32, 64);
            if ((lane >> 4) == 0 && col < N) {
                atomicAdd(&stats[col], cs);
                atomicAdd(&stats[N + col], cq);
            }
        }
    }
}

// ---------------------------------------------------------------------------
// CSR build (dst-sorted). P[v] = end offset after fill.
// ---------------------------------------------------------------------------
__global__ __launch_bounds__(256) void csr_count(const int* __restrict__ dst, int* __restrict__ P)
{
    int e = blockIdx.x * 256 + threadIdx.x;
    if (e < N_EDGES) atomicAdd(&P[dst[e] + 1], 1);
}

__global__ __launch_bounds__(1024) void csr_scan(int* __restrict__ P)
{
    __shared__ int part[1024];
    const int t = threadIdx.x;
    const int CH = 49;
    int i0 = t * CH;
    int s = 0;
    for (int i = i0; i < i0 + CH; ++i) {
        if (i <= N_NODES) { s += P[i]; P[i] = s; }
    }
    part[t] = s;
    __syncthreads();
    if (t == 0) {
        int run = 0;
        for (int k = 0; k < 1024; ++k) { int tmp = part[k]; part[k] = run; run += tmp; }
    }
    __syncthreads();
    int off = part[t];
    for (int i = i0; i < i0 + CH; ++i) {
        if (i <= N_NODES) P[i] += off;
    }
}

__global__ __launch_bounds__(256) void csr_fill(
    const int* __restrict__ dst, int* __restrict__ P, int* __restrict__ eids)
{
    int e = blockIdx.x * 256 + threadIdx.x;
    if (e < N_EDGES) {
        int pos = atomicAdd(&P[dst[e]], 1);
        eids[pos] = e;
    }
}

// ---------------------------------------------------------------------------
// Re-sort src + edge_feat(->bf16) into CSR edge order. Runs once.
// ---------------------------------------------------------------------------
__global__ __launch_bounds__(256) void edge_pack_bf(
    const int* __restrict__ src, const int* __restrict__ eids,
    const float* __restrict__ edge_feat, int* __restrict__ es,
    unsigned short* __restrict__ efsb)
{
    int j = blockIdx.x * 256 + threadIdx.x;
    if (j >= N_EDGES) return;
    int e = eids[j];
    es[j] = src[e];
    const float* sp = edge_feat + (size_t)e * EFEAT;
    us8 o0, o1;
#pragma unroll
    for (int k = 0; k < 8; ++k) {
        o0[k] = f2bf(sp[k]);
        o1[k] = f2bf(sp[8 + k]);
    }
    *(us8*)&efsb[(size_t)j * EFEAT] = o0;
    *(us8*)&efsb[(size_t)j * EFEAT + 8] = o1;
}

// ---------------------------------------------------------------------------
// Gather aggregation v5: ONE wave per node (round-5 proven shape), bf16 hnb
// rows (608B — half the fetch bytes of fp32), edge loop unrolled x2 (10
// outstanding row-chunk loads). Output bf16 [N][320].
// ---------------------------------------------------------------------------
__global__ __launch_bounds__(256) void gather_agg5(
    const unsigned short* __restrict__ hnb, const unsigned short* __restrict__ efsb,
    const int* __restrict__ es, const int* __restrict__ P,
    const float* __restrict__ eW, const float* __restrict__ eb,
    unsigned short* __restrict__ aggH)
{
    const int v = blockIdx.x * 4 + (threadIdx.x >> 6);
    if (v >= N_NODES) return;
    const int lane = threadIdx.x & 63;

    float wr[EFEAT][5];
    float acc[5];
    float ebv[5];
#pragma unroll
    for (int c = 0; c < 5; ++c) {
        int d = lane + 64 * c;
        bool dv = d < DIM;
        acc[c] = dv ? bf2f(hnb[(size_t)v * 304 + d]) : 0.f;
        ebv[c] = dv ? eb[d] : 0.f;
#pragma unroll
        for (int k = 0; k < EFEAT; ++k)
            wr[k][c] = dv ? eW[k * DIM + d] : 0.f;
    }

    const int j0 = (v == 0) ? 0 : P[v - 1];
    const int j1 = P[v];

    int j = j0;
    for (; j + 2 <= j1; j += 2) {
        int s0 = __builtin_amdgcn_readfirstlane(es[j]);
        int s1 = __builtin_amdgcn_readfirstlane(es[j + 1]);
        const unsigned short* __restrict__ h0 = hnb + (size_t)s0 * 304;
        const unsigned short* __restrict__ h1 = hnb + (size_t)s1 * 304;
        float hv0[5], hv1[5];
#pragma unroll
        for (int c = 0; c < 5; ++c) {
            int d = lane + 64 * c;
            bool dv = d < DIM;
            hv0[c] = dv ? bf2f(h0[d]) : 0.f;
            hv1[c] = dv ? bf2f(h1[d]) : 0.f;
        }
        us8 p00 = *(const us8*)&efsb[(size_t)j * EFEAT];
        us8 p01 = *(const us8*)&efsb[(size_t)j * EFEAT + 8];
        us8 p10 = *(const us8*)&efsb[(size_t)(j + 1) * EFEAT];
        us8 p11 = *(const us8*)&efsb[(size_t)(j + 1) * EFEAT + 8];
        float ef0[EFEAT], ef1[EFEAT];
#pragma unroll
        for (int k = 0; k < 8; ++k) {
            ef0[k] = bf2f(p00[k]); ef0[8 + k] = bf2f(p01[k]);
            ef1[k] = bf2f(p10[k]); ef1[8 + k] = bf2f(p11[k]);
        }
#pragma unroll
        for (int c = 0; c < 5; ++c) {
            float he0 = ebv[c], he1 = ebv[c];
#pragma unroll
            for (int k = 0; k < EFEAT; ++k) {
                he0 = fmaf(ef0[k], wr[k][c], he0);
                he1 = fmaf(ef1[k], wr[k][c], he1);
            }
            acc[c] += fmaxf(hv0[c] + he0, 0.f);
            acc[c] += fmaxf(hv1[c] + he1, 0.f);
        }
    }
    if (j < j1) {
        int s = __builtin_amdgcn_readfirstlane(es[j]);
        const unsigned short* __restrict__ hp = hnb + (size_t)s * 304;
        float hv[5];
#pragma unroll
        for (int c = 0; c < 5; ++c) {
            int d = lane + 64 * c;
            hv[c] = (d < DIM) ? bf2f(hp[d]) : 0.f;
        }
        us8 p0 = *(const us8*)&efsb[(size_t)j * EFEAT];
        us8 p1 = *(const us8*)&efsb[(size_t)j * EFEAT + 8];
        float ef0[EFEAT];
#pragma unroll
        for (int k = 0; k < 8; ++k) {
            ef0[k] = bf2f(p0[k]); ef0[8 + k] = bf2f(p1[k]);
        }
#pragma unroll
        for (int c = 0; c < 5; ++c) {
            float he = ebv[c];
#pragma unroll
            for (int k = 0; k < EFEAT; ++k) he = fmaf(ef0[k], wr[k][c], he);
            acc[c] += fmaxf(hv[c] + he, 0.f);
        }
    }

#pragma unroll
    for (int c = 0; c < 5; ++c)
        aggH[(size_t)v * 320 + lane + 64 * c] = f2bf(acc[c]);
}

// ---------------------------------------------------------------------------
// BN finalize + apply (apply dual-writes fp32 hn + optional bf16 hnb[N][304])
// ---------------------------------------------------------------------------
__global__ __launch_bounds__(256) void bn_finalize(
    const float* __restrict__ stats, const float* __restrict__ g,
    const float* __restrict__ beta, float* __restrict__ ab, int C)
{
    int c = blockIdx.x * 256 + threadIdx.x;
    if (c >= C) return;
    const float invN = 1.f / (float)N_NODES;
    float m = stats[c] * invN;
    float v = stats[C + c] * invN - m * m;
    float a = g[c] * rsqrtf(v + BN_EPS);
    ab[c] = a;
    ab[C + c] = beta[c] - m * a;
}

__global__ __launch_bounds__(256) void bn_apply2(
    const float* __restrict__ x, const float* __restrict__ ab,
    float* __restrict__ y, unsigned short* __restrict__ yb,
    int total4, int relu)
{
    int i = blockIdx.x * 256 + threadIdx.x;
    if (i >= total4) return;
    int n = i / 75;              // 300/4 = 75 float4 per row
    int c = (i - n * 75) * 4;
    float4 v = ((const float4*)x)[i];
    const float* a = ab + c;
    const float* bb = ab + DIM + c;
    float4 r;
    r.x = fmaf(v.x, a[0], bb[0]);
    r.y = fmaf(v.y, a[1], bb[1]);
    r.z = fmaf(v.z, a[2], bb[2]);
    r.w = fmaf(v.w, a[3], bb[3]);
    if (relu) {
        r.x = fmaxf(r.x, 0.f); r.y = fmaxf(r.y, 0.f);
        r.z = fmaxf(r.z, 0.f); r.w = fmaxf(r.w, 0.f);
    }
    ((float4*)y)[i] = r;
    if (yb != nullptr) {
        us4 h;
        h.x = f2bf(r.x); h.y = f2bf(r.y); h.z = f2bf(r.z); h.w = f2bf(r.w);
        *(us4*)&yb[(size_t)n * 304 + c] = h;
    }
}

// zero the 4-pad columns of hnb once (rows written by bn_apply2 never touch them)
__global__ __launch_bounds__(256) void hnb_padzero(unsigned short* __restrict__ hnb)
{
    int i = blockIdx.x * 256 + threadIdx.x;
    if (i >= N_NODES * 4) return;
    int n = i >> 2;
    hnb[(size_t)n * 304 + 300 + (i & 3)] = 0;
}

// ---------------------------------------------------------------------------
// Mean pooling: segmented reduction (graph_ids sorted), one block per graph.
// ---------------------------------------------------------------------------
__global__ __launch_bounds__(256) void pool_seg(
    const float* __restrict__ hn, const int* __restrict__ gid,
    float* __restrict__ hg)
{
    const int g = blockIdx.x;
    int lo = 0, hi = N_NODES;
    while (lo < hi) { int mid = (lo + hi) >> 1; if (gid[mid] < g) lo = mid + 1; else hi = mid; }
    int lo2 = lo, hi2 = N_NODES;
    while (lo2 < hi2) { int mid = (lo2 + hi2) >> 1; if (gid[mid] < g + 1) lo2 = mid + 1; else hi2 = mid; }
    const float inv = 1.f / fmaxf((float)(lo2 - lo), 1.f);
    for (int d = threadIdx.x; d < DIM; d += 256) {
        float s = 0.f;
        for (int r = lo; r < lo2; ++r) s += hn[(size_t)r * DIM + d];
        hg[(size_t)g * DIM + d] = s * inv;
    }
}

// fp32 tiled sgemm for the tiny prediction head
#define TS 64
#define BK 16
#define ASP 68

__global__ __launch_bounds__(256) void sgemm_bias(
    const float* __restrict__ A, const float* __restrict__ B,
    const float* __restrict__ bias, float* __restrict__ C,
    int M, int Ncol, int K)
{
    __shared__ float As[BK][ASP];
    __shared__ float Bs[BK][TS];
    const int tid = threadIdx.x;
    const int bm = blockIdx.x * TS;
    const int bn = blockIdx.y * TS;
    const int tm = (tid >> 4) * 4;
    const int tn = (tid & 15) * 4;
    float acc[4][4] = {};

    for (int k0 = 0; k0 < K; k0 += BK) {
#pragma unroll
        for (int i = 0; i < 4; ++i) {
            int idx = tid + i * 256;
            int m = idx >> 4;
            int k = idx & 15;
            int row = bm + m, kk = k0 + k;
            float v = 0.f;
            if (row < M && kk < K) v = A[(size_t)row * K + kk];
            As[k][m] = v;
        }
#pragma unroll
        for (int i = 0; i < 4; ++i) {
            int idx = tid + i * 256;
            int k = idx >> 6;
            int n = idx & 63;
            int col = bn + n, kk = k0 + k;
            float v = 0.f;
            if (col < Ncol && kk < K) v = B[(size_t)kk * Ncol + col];
            Bs[k][n] = v;
        }
        __syncthreads();
#pragma unroll
        for (int k = 0; k < BK; ++k) {
            float4 av = *(const float4*)&As[k][tm];
            float4 bv = *(const float4*)&Bs[k][tn];
            float a4[4] = {av.x, av.y, av.z, av.w};
            float b4[4] = {bv.x, bv.y, bv.z, bv.w};
#pragma unroll
            for (int i = 0; i < 4; ++i)
#pragma unroll
                for (int j = 0; j < 4; ++j)
                    acc[i][j] = fmaf(a4[i], b4[j], acc[i][j]);
        }
        __syncthreads();
    }

#pragma unroll
    for (int i = 0; i < 4; ++i) {
        int row = bm + tm + i;
        if (row >= M) continue;
#pragma unroll
        for (int j = 0; j < 4; ++j) {
            int col = bn + tn + j;
            if (col < Ncol)
                C[(size_t)row * Ncol + col] = acc[i][j] + bias[col];
        }
    }
}

// ---------------------------------------------------------------------------
extern "C" void kernel_launch(void* const* d_in, const int* in_sizes, int n_in,
                              void* d_out, int out_size, void* d_ws, size_t ws_size,
                              hipStream_t stream)
{
    const float* node_feat = (const float*)d_in[0];
    const float* edge_feat = (const float*)d_in[1];
    const int*   src       = (const int*)d_in[2];
    const int*   dst       = (const int*)d_in[3];
    const int*   gid       = (const int*)d_in[4];
    const float* node_W = (const float*)d_in[6];
    const float* node_b = (const float*)d_in[7];
    const float* edge_W = (const float*)d_in[8];
    const float* edge_b = (const float*)d_in[9];
    const float* W1  = (const float*)d_in[10];
    const float* b1  = (const float*)d_in[11];
    const float* g1  = (const float*)d_in[12];
    const float* be1 = (const float*)d_in[13];
    const float* W2  = (const float*)d_in[14];
    const float* b2  = (const float*)d_in[15];
    const float* g2  = (const float*)d_in[16];
    const float* be2 = (const float*)d_in[17];
    const float* pred_W = (const float*)d_in[18];
    const float* pred_b = (const float*)d_in[19];
    float* out = (float*)d_out;

    // ---- workspace layout (bytes), total < 248.73 MB (proven) ----
    // hnb lives in x1's tail [149.6M,180M): x1 is dead from gemm_af(l) until
    // gemm_pp(l+1); hnb written at bn_apply2(l)/encoder-tobf_pad, consumed at
    // gather(l+1) — strictly inside x1's dead window.
    char* base = (char*)d_ws;
    float* hn            = (float*)(base + 0);                 // 60,000,000
    float* h2            = hn;                                 // in-place
    float* x1            = (float*)(base + 60000000);          // 120,000,000
    unsigned short* nfH  = (unsigned short*)x1;                // alias (encoder only)
    unsigned short* hnb  = (unsigned short*)(base + 149600000);// 30,400,000 (x1 tail alias)
    unsigned short* aggH = (unsigned short*)(base + 180000000);// 32,000,000
    int*   es            = (int*)(base + 212000000);           // 3,200,000
    unsigned short* efsb = (unsigned short*)(base + 215200000);// 25,600,000
    unsigned short* wtH  = (unsigned short*)(base + 244000000);
    unsigned short* wtL  = (unsigned short*)(base + 244500000);
    int*   eids          = (int*)(base + 245000000);           // 3,200,000
    int*   P             = (int*)(base + 248200000);           // 200,004
    float* stats         = (float*)(base + 248400016);
    float* ab            = (float*)(base + 248407216);
    float* hg            = (float*)(base + 248414416);         // 307,200
    float* stats2        = stats + 1200;
    float* ab2           = ab + 1200;

    dim3 blk(256);

    // ---- node encoder: hn = node_feat @ node_W + node_b; hnb = bf16(hn) ----
    tobf4<<<dim3((N_NODES * NFEAT / 4 + 255) / 256), blk, 0, stream>>>(
        node_feat, nfH, N_NODES * NFEAT / 4);
    conv_wt<<<dim3((384 * 128 + 255) / 256), blk, 0, stream>>>(
        node_W, wtH, wtL, NFEAT, DIM, 128, 384);
    gemm_pp<<<dim3(391, 3), blk, 0, stream>>>(
        nfH, wtH, wtL, node_b, hn, N_NODES, DIM, 128, nullptr);
    tobf_pad<<<dim3((N_NODES * 304 + 255) / 256), blk, 0, stream>>>(hn, hnb);

    // ---- CSR by dst + packed edge streams (layer-invariant, run once) ----
    hipMemsetAsync(P, 0, (N_NODES + 1) * sizeof(int), stream);
    csr_count<<<dim3((N_EDGES + 255) / 256), blk, 0, stream>>>(dst, P);
    csr_scan<<<dim3(1), dim3(1024), 0, stream>>>(P);
    csr_fill<<<dim3((N_EDGES + 255) / 256), blk, 0, stream>>>(dst, P, eids);
    edge_pack_bf<<<dim3((N_EDGES + 255) / 256), blk, 0, stream>>>(
        src, eids, edge_feat, es, efsb);

    for (int l = 0; l < N_LAYERS; ++l) {
        // aggH = bf16(hn + sum relu(hn[src] + he))  [N][320]
        gather_agg5<<<dim3((N_NODES + 3) / 4), blk, 0, stream>>>(
            hnb, efsb, es, P,
            edge_W + (size_t)l * EFEAT * DIM, edge_b + (size_t)l * DIM, aggH);

        hipMemsetAsync(stats, 0, 1800 * sizeof(float), stream);

        // x1 = agg @ W1 + b1   [N, 600]  (+ BN1 stats in epilogue)
        conv_wt<<<dim3((640 * 320 + 255) / 256), blk, 0, stream>>>(
            W1 + (size_t)l * DIM * 2 * DIM, wtH, wtL, DIM, 2 * DIM, 320, 640);
        gemm_pp<<<dim3(391, 5), blk, 0, stream>>>(
            aggH, wtH, wtL, b1 + (size_t)l * 2 * DIM, x1,
            N_NODES, 2 * DIM, 320, stats);
        bn_finalize<<<dim3(3), blk, 0, stream>>>(
            stats, g1 + (size_t)l * 2 * DIM, be1 + (size_t)l * 2 * DIM, ab, 2 * DIM);

        // h2(=hn) = relu(bn1(x1)) @ W2 + b2  (split-A 3-MFMA; BN2 stats epi)
        conv_wt<<<dim3((384 * 608 + 255) / 256), blk, 0, stream>>>(
            W2 + (size_t)l * 2 * DIM * DIM, wtH, wtL, 2 * DIM, DIM, 608, 384);
        gemm_af<<<dim3(391, 3), blk, 0, stream>>>(
            x1, wtH, wtL, b2 + (size_t)l * DIM, h2, N_NODES, DIM, 2 * DIM, 608,
            ab, stats2);
        bn_finalize<<<dim3(2), blk, 0, stream>>>(
            stats2, g2 + (size_t)l * DIM, be2 + (size_t)l * DIM, ab2, DIM);

        // hn = bn2(h2) (+relu except last), dual-write hnb for next gather
        bool last = (l == N_LAYERS - 1);
        bn_apply2<<<dim3((N_NODES * DIM / 4 + 255) / 256), blk, 0, stream>>>(
            h2, ab2, hn, last ? (unsigned short*)nullptr : hnb,
            N_NODES * DIM / 4, last ? 0 : 1);
        if (!last)
            hnb_padzero<<<dim3((N_NODES * 4 + 255) / 256), blk, 0, stream>>>(hnb);
    }

    // ---- mean pool (segmented) + head ----
    pool_seg<<<dim3(N_GRAPHS), blk, 0, stream>>>(hn, gid, hg);
    sgemm_bias<<<dim3((N_GRAPHS + 63) / 64, (OUTD + 63) / 64), blk, 0, stream>>>(
        hg, pred_W, pred_b, out, N_GRAPHS, OUTD, DIM);
}

// Round 9
// 2198.637 us; speedup vs baseline: 1.2067x; 1.2067x over previous
//
#include <hip/hip_runtime.h>

#define N_NODES 50000
#define N_EDGES 800000
#define N_GRAPHS 256
#define N_LAYERS 3
#define DIM 300
#define NFEAT 128
#define EFEAT 16
#define OUTD 128
#define BN_EPS 1e-5f

typedef __attribute__((ext_vector_type(8))) short bfrag8;   // 8 bf16 = 4 VGPR (MFMA A/B operand)
typedef __attribute__((ext_vector_type(4))) float facc4;    // MFMA C/D
typedef __attribute__((ext_vector_type(4))) unsigned short us4;
typedef __attribute__((ext_vector_type(8))) unsigned short us8;

// ---------------- bf16 helpers (RNE) + hi/lo split ----------------
__device__ __forceinline__ unsigned short f2bf(float f) {
    unsigned u = __float_as_uint(f);
    unsigned r = ((u >> 16) & 1u) + 0x7fffu;
    return (unsigned short)((u + r) >> 16);
}
__device__ __forceinline__ float bf2f(unsigned short h) {
    return __uint_as_float(((unsigned)h) << 16);
}
__device__ __forceinline__ void split2(float v, unsigned short& h, unsigned short& l) {
    h = f2bf(v);
    l = f2bf(v - bf2f(h));
}

// async global->LDS, 16B per lane. LDS dest = uniform base + lane*16 (HW rule).
__device__ __forceinline__ void load_lds16(const void* gsrc, void* ldsdst) {
    __builtin_amdgcn_global_load_lds(
        (const __attribute__((address_space(1))) unsigned int*)gsrc,
        (__attribute__((address_space(3))) unsigned int*)ldsdst,
        16, 0, 0);
}

#define MFMA16(a, b, c) __builtin_amdgcn_mfma_f32_16x16x32_bf16(a, b, c, 0, 0, 0)

// ---------------------------------------------------------------------------
// fp32 -> bf16 (hi only), vectorized
// ---------------------------------------------------------------------------
__global__ __launch_bounds__(256) void tobf4(
    const float* __restrict__ x, unsigned short* __restrict__ H, int n4)
{
    int i = blockIdx.x * 256 + threadIdx.x;
    if (i >= n4) return;
    float4 v = ((const float4*)x)[i];
    us4 h;
    h.x = f2bf(v.x); h.y = f2bf(v.y); h.z = f2bf(v.z); h.w = f2bf(v.w);
    ((us4*)H)[i] = h;
}

// ---------------------------------------------------------------------------
// weight conversion: W fp32 [K][N] -> transposed padded hi/lo planes [Np][Kp]
// ---------------------------------------------------------------------------
__global__ __launch_bounds__(256) void conv_wt(
    const float* __restrict__ W, unsigned short* __restrict__ H,
    unsigned short* __restrict__ L, int K, int N, int Kp, int Np)
{
    int idx = blockIdx.x * 256 + threadIdx.x;
    if (idx >= Np * Kp) return;
    int n = idx / Kp;
    int k = idx - n * Kp;
    float v = (n < N && k < K) ? W[(size_t)k * N + n] : 0.f;
    unsigned short h, l;
    split2(v, h, l);
    H[idx] = h;
    L[idx] = l;
}

// ---------------------------------------------------------------------------
// bf16 MFMA GEMM: A plain bf16 [M][Kp]; B transposed hi/lo planes [Np][Kp].
// acc = Ah*Bh + Ah*Bl (2 MFMA/tile). Block 128x128, BK=32, 4 waves 2x2.
// LDS 24KB: A 8KB | Bh 8KB | Bl 8KB. Optional column-stat epilogue (BN).
// ---------------------------------------------------------------------------
__global__ __launch_bounds__(256, 2) void gemm_pp(
    const unsigned short* __restrict__ Ah,
    const unsigned short* __restrict__ Bth, const unsigned short* __restrict__ Btl,
    const float* __restrict__ bias, float* __restrict__ C,
    int M, int N, int Kp, float* __restrict__ stats)
{
    __shared__ unsigned short lds[12288];   // 24 KB
    const int tid = threadIdx.x;
    const int lane = tid & 63;
    const int w = tid >> 6;
    const int m0 = blockIdx.x * 128;
    const int n0 = blockIdx.y * 128;
    const int wm = (w & 1) * 64;
    const int wn = (w >> 1) * 64;

    const int srow = lane >> 2;
    const int scol = (lane & 3) * 8;

    const unsigned short* gp[6];
    unsigned loff[6];
#pragma unroll
    for (int i = 0; i < 6; ++i) {
        int c = w * 6 + i;
        const unsigned short* pl = (c < 8) ? Ah : (c < 16) ? Bth : Btl;
        int rowg;
        if (c < 8) {
            rowg = m0 + (c & 7) * 16 + srow;
            rowg = min(rowg, M - 1);
        } else {
            rowg = n0 + (c & 7) * 16 + srow;
        }
        gp[i] = pl + (size_t)rowg * Kp + scol;
        loff[i] = c * 512;
    }

    facc4 acc[4][4];
    facc4 zero = {0.f, 0.f, 0.f, 0.f};
#pragma unroll
    for (int i = 0; i < 4; ++i)
#pragma unroll
        for (int j = 0; j < 4; ++j) acc[i][j] = zero;

    const int fr = lane & 15;
    const int fq = (lane >> 4) * 8;

    for (int k0 = 0; k0 < Kp; k0 += 32) {
#pragma unroll
        for (int i = 0; i < 6; ++i) {
            load_lds16(gp[i], &lds[loff[i]]);
            gp[i] += 32;
        }
        __syncthreads();

        bfrag8 ah[4], bh[4], bl[4];
#pragma unroll
        for (int t = 0; t < 4; ++t) {
            int ar = wm + t * 16 + fr;
            ah[t] = *(const bfrag8*)&lds[ar * 32 + fq];
            int br = wn + t * 16 + fr;
            bh[t] = *(const bfrag8*)&lds[4096 + br * 32 + fq];
            bl[t] = *(const bfrag8*)&lds[8192 + br * 32 + fq];
        }
#pragma unroll
        for (int i = 0; i < 4; ++i)
#pragma unroll
            for (int j = 0; j < 4; ++j) {
                acc[i][j] = MFMA16(ah[i], bh[j], acc[i][j]);
                acc[i][j] = MFMA16(ah[i], bl[j], acc[i][j]);
            }
        __syncthreads();
    }

    // epilogue: C/D layout col=lane&15, row=(lane>>4)*4+reg
#pragma unroll
    for (int i = 0; i < 4; ++i)
#pragma unroll
        for (int j = 0; j < 4; ++j) {
            int col = n0 + wn + j * 16 + (lane & 15);
            if (col >= N) continue;
            float bv = bias[col];
#pragma unroll
            for (int r = 0; r < 4; ++r) {
                int row = m0 + wm + i * 16 + (lane >> 4) * 4 + r;
                if (row < M)
                    C[(size_t)row * N + col] = acc[i][j][r] + bv;
            }
        }

    if (stats != nullptr) {
#pragma unroll
        for (int j = 0; j < 4; ++j) {
            int col = n0 + wn + j * 16 + (lane & 15);
            float cs = 0.f, cq = 0.f;
            if (col < N) {
                float bv = bias[col];
#pragma unroll
                for (int i = 0; i < 4; ++i)
#pragma unroll
                    for (int r = 0; r < 4; ++r) {
                        int row = m0 + wm + i * 16 + (lane >> 4) * 4 + r;
                        if (row < M) {
                            float y = acc[i][j][r] + bv;
                            cs += y;
                            cq = fmaf(y, y, cq);
                        }
                    }
            }
            cs += __shfl_xor(cs, 16, 64); cq += __shfl_xor(cq, 16, 64);
            cs += __shfl_xor(cs, 32, 64); cq += __shfl_xor(cq, 32, 64);
            if ((lane >> 4) == 0 && col < N) {
                atomicAdd(&stats[col], cs);
                atomicAdd(&stats[N + col], cq);
            }
        }
    }
}

// ---------------------------------------------------------------------------
// bf16 MFMA GEMM, A fp32 with fused BN-affine+ReLU applied during staging
// (abn = [a K | b K], y = relu(x*a+b)) -> bf16 hi only (r7-proven accuracy).
// LDS 24KB: A | Bh | Bl. Column-stat epilogue for BN2.
// ---------------------------------------------------------------------------
__global__ __launch_bounds__(256, 2) void gemm_af(
    const float* __restrict__ A, const unsigned short* __restrict__ Bth,
    const unsigned short* __restrict__ Btl, const float* __restrict__ bias,
    float* __restrict__ C, int M, int N, int K, int Kp,
    const float* __restrict__ abn, float* __restrict__ stats)
{
    __shared__ unsigned short lds[12288];
    const int tid = threadIdx.x;
    const int lane = tid & 63;
    const int w = tid >> 6;
    const int m0 = blockIdx.x * 128;
    const int n0 = blockIdx.y * 128;
    const int wm = (w & 1) * 64;
    const int wn = (w >> 1) * 64;

    const int srow = lane >> 2;
    const int scol = (lane & 3) * 8;

    const unsigned short* gpb[4];
    unsigned loffb[4];
#pragma unroll
    for (int i = 0; i < 4; ++i) {
        int c = w * 4 + i;
        const unsigned short* pl = (c < 8) ? Bth : Btl;
        int rowg = n0 + (c & 7) * 16 + srow;
        gpb[i] = pl + (size_t)rowg * Kp + scol;
        loffb[i] = 4096 + c * 512;
    }

    facc4 acc[4][4];
    facc4 zero = {0.f, 0.f, 0.f, 0.f};
#pragma unroll
    for (int i = 0; i < 4; ++i)
#pragma unroll
        for (int j = 0; j < 4; ++j) acc[i][j] = zero;

    const int fr = lane & 15;
    const int fq = (lane >> 4) * 8;

    for (int k0 = 0; k0 < Kp; k0 += 32) {
#pragma unroll
        for (int i = 0; i < 4; ++i) {
            load_lds16(gpb[i], &lds[loffb[i]]);
            gpb[i] += 32;
        }
        // A fp32 -> BN affine + relu -> bf16 into LDS (128 rows x 32 k)
#pragma unroll
        for (int i = 0; i < 4; ++i) {
            int idx = tid + i * 256;
            int row = idx >> 3;
            int q4 = idx & 7;
            int rg = min(m0 + row, M - 1);
            int kk = k0 + q4 * 4;
            us4 h;
            if (kk < K) {
                float4 v = *(const float4*)&A[(size_t)rg * K + kk];
                float4 sa = *(const float4*)&abn[kk];
                float4 sb = *(const float4*)&abn[K + kk];
                h.x = f2bf(fmaxf(fmaf(v.x, sa.x, sb.x), 0.f));
                h.y = f2bf(fmaxf(fmaf(v.y, sa.y, sb.y), 0.f));
                h.z = f2bf(fmaxf(fmaf(v.z, sa.z, sb.z), 0.f));
                h.w = f2bf(fmaxf(fmaf(v.w, sa.w, sb.w), 0.f));
            } else {
                h.x = 0; h.y = 0; h.z = 0; h.w = 0;
            }
            *(us4*)&lds[row * 32 + q4 * 4] = h;
        }
        __syncthreads();

        bfrag8 ah[4], bh[4], bl[4];
#pragma unroll
        for (int t = 0; t < 4; ++t) {
            int ar = wm + t * 16 + fr;
            ah[t] = *(const bfrag8*)&lds[ar * 32 + fq];
            int br = wn + t * 16 + fr;
            bh[t] = *(const bfrag8*)&lds[4096 + br * 32 + fq];
            bl[t] = *(const bfrag8*)&lds[8192 + br * 32 + fq];
        }
#pragma unroll
        for (int i = 0; i < 4; ++i)
#pragma unroll
            for (int j = 0; j < 4; ++j) {
                acc[i][j] = MFMA16(ah[i], bh[j], acc[i][j]);
                acc[i][j] = MFMA16(ah[i], bl[j], acc[i][j]);
            }
        __syncthreads();
    }

#pragma unroll
    for (int i = 0; i < 4; ++i)
#pragma unroll
        for (int j = 0; j < 4; ++j) {
            int col = n0 + wn + j * 16 + (lane & 15);
            if (col >= N) continue;
            float bv = bias[col];
#pragma unroll
            for (int r = 0; r < 4; ++r) {
                int row = m0 + wm + i * 16 + (lane >> 4) * 4 + r;
                if (row < M)
                    C[(size_t)row * N + col] = acc[i][j][r] + bv;
            }
        }

    if (stats != nullptr) {
#pragma unroll
        for (int j = 0; j < 4; ++j) {
            int col = n0 + wn + j * 16 + (lane & 15);
            float cs = 0.f, cq = 0.f;
            if (col < N) {
                float bv = bias[col];
#pragma unroll
                for (int i = 0; i < 4; ++i)
#pragma unroll
                    for (int r = 0; r < 4; ++r) {
                        int row = m0 + wm + i * 16 + (lane >> 4) * 4 + r;
                        if (row < M) {
                            float y = acc[i][j][r] + bv;
                            cs += y;
                            cq = fmaf(y, y, cq);
                        }
                    }
            }
            cs += __shfl_xor(cs, 16, 64); cq += __shfl_xor(cq, 16, 64);
            cs += __shfl_xor(cs, 32, 64); cq += __shfl_xor(cq, 32, 64);
            if ((lane >> 4) == 0 && col < N) {
                atomicAdd(&stats[col], cs);
                atomicAdd(&stats[N + col], cq);
            }
        }
    }
}

// ---------------------------------------------------------------------------
// CSR build (dst-sorted). P[v] = end offset after fill.
// ---------------------------------------------------------------------------
__global__ __launch_bounds__(256) void csr_count(const int* __restrict__ dst, int* __restrict__ P)
{
    int e = blockIdx.x * 256 + threadIdx.x;
    if (e < N_EDGES) atomicAdd(&P[dst[e] + 1], 1);
}

__global__ __launch_bounds__(1024) void csr_scan(int* __restrict__ P)
{
    __shared__ int part[1024];
    const int t = threadIdx.x;
    const int CH = 49;
    int i0 = t * CH;
    int s = 0;
    for (int i = i0; i < i0 + CH; ++i) {
        if (i <= N_NODES) { s += P[i]; P[i] = s; }
    }
    part[t] = s;
    __syncthreads();
    if (t == 0) {
        int run = 0;
        for (int k = 0; k < 1024; ++k) { int tmp = part[k]; part[k] = run; run += tmp; }
    }
    __syncthreads();
    int off = part[t];
    for (int i = i0; i < i0 + CH; ++i) {
        if (i <= N_NODES) P[i] += off;
    }
}

__global__ __launch_bounds__(256) void csr_fill(
    const int* __restrict__ dst, int* __restrict__ P, int* __restrict__ eids)
{
    int e = blockIdx.x * 256 + threadIdx.x;
    if (e < N_EDGES) {
        int pos = atomicAdd(&P[dst[e]], 1);
        eids[pos] = e;
    }
}

// ---------------------------------------------------------------------------
// Re-sort src + edge_feat(->bf16) into CSR edge order. Runs once.
// ---------------------------------------------------------------------------
__global__ __launch_bounds__(256) void edge_pack_bf(
    const int* __restrict__ src, const int* __restrict__ eids,
    const float* __restrict__ edge_feat, int* __restrict__ es,
    unsigned short* __restrict__ efsb)
{
    int j = blockIdx.x * 256 + threadIdx.x;
    if (j >= N_EDGES) return;
    int e = eids[j];
    es[j] = src[e];
    const float* sp = edge_feat + (size_t)e * EFEAT;
    us8 o0, o1;
#pragma unroll
    for (int k = 0; k < 8; ++k) {
        o0[k] = f2bf(sp[k]);
        o1[k] = f2bf(sp[8 + k]);
    }
    *(us8*)&efsb[(size_t)j * EFEAT] = o0;
    *(us8*)&efsb[(size_t)j * EFEAT + 8] = o1;
}

// ---------------------------------------------------------------------------
// Gather aggregation v7: ONE wave per node, fp32 hn rows (contiguous 1.2KB),
// edge loop unrolled x4 -> 20 outstanding 256B row loads per wave (MLP is the
// binding constraint per r8 counters: halving bytes did NOT help; more
// outstanding requests should). ef bf16 persistent stream. Out bf16 [N][320].
// ---------------------------------------------------------------------------
__global__ __launch_bounds__(256) void gather_agg7(
    const float* __restrict__ hn, const unsigned short* __restrict__ efsb,
    const int* __restrict__ es, const int* __restrict__ P,
    const float* __restrict__ eW, const float* __restrict__ eb,
    unsigned short* __restrict__ aggH)
{
    const int v = blockIdx.x * 4 + (threadIdx.x >> 6);
    if (v >= N_NODES) return;
    const int lane = threadIdx.x & 63;

    float wr[EFEAT][5];
    float acc[5];
    float ebv[5];
#pragma unroll
    for (int c = 0; c < 5; ++c) {
        int d = lane + 64 * c;
        bool dv = d < DIM;
        acc[c] = dv ? hn[(size_t)v * DIM + d] : 0.f;
        ebv[c] = dv ? eb[d] : 0.f;
#pragma unroll
        for (int k = 0; k < EFEAT; ++k)
            wr[k][c] = dv ? eW[k * DIM + d] : 0.f;
    }

    const int j0 = (v == 0) ? 0 : P[v - 1];
    const int j1 = P[v];

    int j = j0;
    for (; j + 4 <= j1; j += 4) {
        int s0 = __builtin_amdgcn_readfirstlane(es[j]);
        int s1 = __builtin_amdgcn_readfirstlane(es[j + 1]);
        int s2 = __builtin_amdgcn_readfirstlane(es[j + 2]);
        int s3 = __builtin_amdgcn_readfirstlane(es[j + 3]);
        const float* __restrict__ h0 = hn + (size_t)s0 * DIM;
        const float* __restrict__ h1 = hn + (size_t)s1 * DIM;
        const float* __restrict__ h2p = hn + (size_t)s2 * DIM;
        const float* __restrict__ h3 = hn + (size_t)s3 * DIM;
        float hv[4][5];
#pragma unroll
        for (int c = 0; c < 5; ++c) {
            int d = lane + 64 * c;
            bool dv = d < DIM;
            hv[0][c] = dv ? h0[d] : 0.f;
            hv[1][c] = dv ? h1[d] : 0.f;
            hv[2][c] = dv ? h2p[d] : 0.f;
            hv[3][c] = dv ? h3[d] : 0.f;
        }
        us8 pk[4][2];
#pragma unroll
        for (int u = 0; u < 4; ++u) {
            pk[u][0] = *(const us8*)&efsb[(size_t)(j + u) * EFEAT];
            pk[u][1] = *(const us8*)&efsb[(size_t)(j + u) * EFEAT + 8];
        }
#pragma unroll
        for (int u = 0; u < 4; ++u) {
            float ef[EFEAT];
#pragma unroll
            for (int k = 0; k < 8; ++k) {
                ef[k] = bf2f(pk[u][0][k]);
                ef[8 + k] = bf2f(pk[u][1][k]);
            }
#pragma unroll
            for (int c = 0; c < 5; ++c) {
                float he = ebv[c];
#pragma unroll
                for (int k = 0; k < EFEAT; ++k) he = fmaf(ef[k], wr[k][c], he);
                acc[c] += fmaxf(hv[u][c] + he, 0.f);
            }
        }
    }
    for (; j < j1; ++j) {
        int s = __builtin_amdgcn_readfirstlane(es[j]);
        const float* __restrict__ hp = hn + (size_t)s * DIM;
        float hv[5];
#pragma unroll
        for (int c = 0; c < 5; ++c) {
            int d = lane + 64 * c;
            hv[c] = (d < DIM) ? hp[d] : 0.f;
        }
        us8 p0 = *(const us8*)&efsb[(size_t)j * EFEAT];
        us8 p1 = *(const us8*)&efsb[(size_t)j * EFEAT + 8];
        float ef[EFEAT];
#pragma unroll
        for (int k = 0; k < 8; ++k) {
            ef[k] = bf2f(p0[k]);
            ef[8 + k] = bf2f(p1[k]);
        }
#pragma unroll
        for (int c = 0; c < 5; ++c) {
            float he = ebv[c];
#pragma unroll
            for (int k = 0; k < EFEAT; ++k) he = fmaf(ef[k], wr[k][c], he);
            acc[c] += fmaxf(hv[c] + he, 0.f);
        }
    }

#pragma unroll
    for (int c = 0; c < 5; ++c)
        aggH[(size_t)v * 320 + lane + 64 * c] = f2bf(acc[c]);
}

// ---------------------------------------------------------------------------
// BN finalize + apply
// ---------------------------------------------------------------------------
__global__ __launch_bounds__(256) void bn_finalize(
    const float* __restrict__ stats, const float* __restrict__ g,
    const float* __restrict__ beta, float* __restrict__ ab, int C)
{
    int c = blockIdx.x * 256 + threadIdx.x;
    if (c >= C) return;
    const float invN = 1.f / (float)N_NODES;
    float m = stats[c] * invN;
    float v = stats[C + c] * invN - m * m;
    float a = g[c] * rsqrtf(v + BN_EPS);
    ab[c] = a;
    ab[C + c] = beta[c] - m * a;
}

__global__ __launch_bounds__(256) void bn_apply(
    const float* __restrict__ x, const float* __restrict__ ab,
    float* __restrict__ y, int total4, int C, int relu)
{
    int i = blockIdx.x * 256 + threadIdx.x;
    if (i >= total4) return;
    float4 v = ((const float4*)x)[i];
    int c = (i << 2) % C;
    const float* a = ab + c;
    const float* bb = ab + C + c;
    float4 r;
    r.x = fmaf(v.x, a[0], bb[0]);
    r.y = fmaf(v.y, a[1], bb[1]);
    r.z = fmaf(v.z, a[2], bb[2]);
    r.w = fmaf(v.w, a[3], bb[3]);
    if (relu) {
        r.x = fmaxf(r.x, 0.f); r.y = fmaxf(r.y, 0.f);
        r.z = fmaxf(r.z, 0.f); r.w = fmaxf(r.w, 0.f);
    }
    ((float4*)y)[i] = r;
}

// ---------------------------------------------------------------------------
// Mean pooling fused with last BN affine: hg = a*mean(h2)+b (BN is linear,
// so affine commutes with the mean). One block per graph.
// ---------------------------------------------------------------------------
__global__ __launch_bounds__(256) void pool_seg_bn(
    const float* __restrict__ h2, const int* __restrict__ gid,
    const float* __restrict__ ab, float* __restrict__ hg)
{
    const int g = blockIdx.x;
    int lo = 0, hi = N_NODES;
    while (lo < hi) { int mid = (lo + hi) >> 1; if (gid[mid] < g) lo = mid + 1; else hi = mid; }
    int lo2 = lo, hi2 = N_NODES;
    while (lo2 < hi2) { int mid = (lo2 + hi2) >> 1; if (gid[mid] < g + 1) lo2 = mid + 1; else hi2 = mid; }
    const float inv = 1.f / fmaxf((float)(lo2 - lo), 1.f);
    for (int d = threadIdx.x; d < DIM; d += 256) {
        float s = 0.f;
        for (int r = lo; r < lo2; ++r) s += h2[(size_t)r * DIM + d];
        hg[(size_t)g * DIM + d] = fmaf(s * inv, ab[d], ab[DIM + d]);
    }
}

// fp32 tiled sgemm for the tiny prediction head
#define TS 64
#define BK 16
#define ASP 68

__global__ __launch_bounds__(256) void sgemm_bias(
    const float* __restrict__ A, const float* __restrict__ B,
    const float* __restrict__ bias, float* __restrict__ C,
    int M, int Ncol, int K)
{
    __shared__ float As[BK][ASP];
    __shared__ float Bs[BK][TS];
    const int tid = threadIdx.x;
    const int bm = blockIdx.x * TS;
    const int bn = blockIdx.y * TS;
    const int tm = (tid >> 4) * 4;
    const int tn = (tid & 15) * 4;
    float acc[4][4] = {};

    for (int k0 = 0; k0 < K; k0 += BK) {
#pragma unroll
        for (int i = 0; i < 4; ++i) {
            int idx = tid + i * 256;
            int m = idx >> 4;
            int k = idx & 15;
            int row = bm + m, kk = k0 + k;
            float v = 0.f;
            if (row < M && kk < K) v = A[(size_t)row * K + kk];
            As[k][m] = v;
        }
#pragma unroll
        for (int i = 0; i < 4; ++i) {
            int idx = tid + i * 256;
            int k = idx >> 6;
            int n = idx & 63;
            int col = bn + n, kk = k0 + k;
            float v = 0.f;
            if (col < Ncol && kk < K) v = B[(size_t)kk * Ncol + col];
            Bs[k][n] = v;
        }
        __syncthreads();
#pragma unroll
        for (int k = 0; k < BK; ++k) {
            float4 av = *(const float4*)&As[k][tm];
            float4 bv = *(const float4*)&Bs[k][tn];
            float a4[4] = {av.x, av.y, av.z, av.w};
            float b4[4] = {bv.x, bv.y, bv.z, bv.w};
#pragma unroll
            for (int i = 0; i < 4; ++i)
#pragma unroll
                for (int j = 0; j < 4; ++j)
                    acc[i][j] = fmaf(a4[i], b4[j], acc[i][j]);
        }
        __syncthreads();
    }

#pragma unroll
    for (int i = 0; i < 4; ++i) {
        int row = bm + tm + i;
        if (row >= M) continue;
#pragma unroll
        for (int j = 0; j < 4; ++j) {
            int col = bn + tn + j;
            if (col < Ncol)
                C[(size_t)row * Ncol + col] = acc[i][j] + bias[col];
        }
    }
}

// ---------------------------------------------------------------------------
extern "C" void kernel_launch(void* const* d_in, const int* in_sizes, int n_in,
                              void* d_out, int out_size, void* d_ws, size_t ws_size,
                              hipStream_t stream)
{
    const float* node_feat = (const float*)d_in[0];
    const float* edge_feat = (const float*)d_in[1];
    const int*   src       = (const int*)d_in[2];
    const int*   dst       = (const int*)d_in[3];
    const int*   gid       = (const int*)d_in[4];
    const float* node_W = (const float*)d_in[6];
    const float* node_b = (const float*)d_in[7];
    const float* edge_W = (const float*)d_in[8];
    const float* edge_b = (const float*)d_in[9];
    const float* W1  = (const float*)d_in[10];
    const float* b1  = (const float*)d_in[11];
    const float* g1  = (const float*)d_in[12];
    const float* be1 = (const float*)d_in[13];
    const float* W2  = (const float*)d_in[14];
    const float* b2  = (const float*)d_in[15];
    const float* g2  = (const float*)d_in[16];
    const float* be2 = (const float*)d_in[17];
    const float* pred_W = (const float*)d_in[18];
    const float* pred_b = (const float*)d_in[19];
    float* out = (float*)d_out;

    // ---- workspace layout (bytes), total < 248.73 MB (proven ceiling) ----
    char* base = (char*)d_ws;
    float* hn            = (float*)(base + 0);                 // 60,000,000
    float* h2            = hn;                                 // in-place (hn dead after gather)
    float* x1            = (float*)(base + 60000000);          // 120,000,000
    unsigned short* nfH  = (unsigned short*)x1;                // alias (encoder only)
    unsigned short* aggH = (unsigned short*)(base + 180000000);// 32,000,000
    int*   es            = (int*)(base + 212000000);           // 3,200,000
    unsigned short* efsb = (unsigned short*)(base + 215200000);// 25,600,000
    unsigned short* wtH  = (unsigned short*)(base + 244000000);
    unsigned short* wtL  = (unsigned short*)(base + 244500000);
    int*   eids          = (int*)(base + 245000000);           // 3,200,000
    int*   P             = (int*)(base + 248200000);           // 200,004
    float* stats         = (float*)(base + 248400016);
    float* ab            = (float*)(base + 248407216);
    float* hg            = (float*)(base + 248414416);         // 307,200
    float* stats2        = stats + 1200;
    float* ab2           = ab + 1200;

    dim3 blk(256);

    // ---- node encoder: hn = node_feat @ node_W + node_b ----
    tobf4<<<dim3((N_NODES * NFEAT / 4 + 255) / 256), blk, 0, stream>>>(
        node_feat, nfH, N_NODES * NFEAT / 4);
    conv_wt<<<dim3((384 * 128 + 255) / 256), blk, 0, stream>>>(
        node_W, wtH, wtL, NFEAT, DIM, 128, 384);
    gemm_pp<<<dim3(391, 3), blk, 0, stream>>>(
        nfH, wtH, wtL, node_b, hn, N_NODES, DIM, 128, nullptr);

    // ---- CSR by dst + packed edge streams (layer-invariant, run once) ----
    hipMemsetAsync(P, 0, (N_NODES + 1) * sizeof(int), stream);
    csr_count<<<dim3((N_EDGES + 255) / 256), blk, 0, stream>>>(dst, P);
    csr_scan<<<dim3(1), dim3(1024), 0, stream>>>(P);
    csr_fill<<<dim3((N_EDGES + 255) / 256), blk, 0, stream>>>(dst, P, eids);
    edge_pack_bf<<<dim3((N_EDGES + 255) / 256), blk, 0, stream>>>(
        src, eids, edge_feat, es, efsb);

    for (int l = 0; l < N_LAYERS; ++l) {
        // aggH = bf16(hn + sum relu(hn[src] + he))  [N][320]
        gather_agg7<<<dim3((N_NODES + 3) / 4), blk, 0, stream>>>(
            hn, efsb, es, P,
            edge_W + (size_t)l * EFEAT * DIM, edge_b + (size_t)l * DIM, aggH);

        hipMemsetAsync(stats, 0, 1800 * sizeof(float), stream);

        // x1 = agg @ W1 + b1   [N, 600]  (+ BN1 stats in epilogue)
        conv_wt<<<dim3((640 * 320 + 255) / 256), blk, 0, stream>>>(
            W1 + (size_t)l * DIM * 2 * DIM, wtH, wtL, DIM, 2 * DIM, 320, 640);
        gemm_pp<<<dim3(391, 5), blk, 0, stream>>>(
            aggH, wtH, wtL, b1 + (size_t)l * 2 * DIM, x1,
            N_NODES, 2 * DIM, 320, stats);
        bn_finalize<<<dim3(3), blk, 0, stream>>>(
            stats, g1 + (size_t)l * 2 * DIM, be1 + (size_t)l * 2 * DIM, ab, 2 * DIM);

        // h2(=hn) = relu(bn1(x1)) @ W2 + b2  (BN1 fused in staging; BN2 stats)
        conv_wt<<<dim3((384 * 608 + 255) / 256), blk, 0, stream>>>(
            W2 + (size_t)l * 2 * DIM * DIM, wtH, wtL, 2 * DIM, DIM, 608, 384);
        gemm_af<<<dim3(391, 3), blk, 0, stream>>>(
            x1, wtH, wtL, b2 + (size_t)l * DIM, h2, N_NODES, DIM, 2 * DIM, 608,
            ab, stats2);
        bn_finalize<<<dim3(2), blk, 0, stream>>>(
            stats2, g2 + (size_t)l * DIM, be2 + (size_t)l * DIM, ab2, DIM);

        // hn = bn2(h2) + relu, in place — except last layer (fused into pool)
        if (l < N_LAYERS - 1)
            bn_apply<<<dim3((N_NODES * DIM / 4 + 255) / 256), blk, 0, stream>>>(
                h2, ab2, hn, N_NODES * DIM / 4, DIM, 1);
    }

    // ---- mean pool with fused last-BN affine + head ----
    pool_seg_bn<<<dim3(N_GRAPHS), blk, 0, stream>>>(h2, gid, ab2, hg);
    sgemm_bias<<<dim3((N_GRAPHS + 63) / 64, (OUTD + 63) / 64), blk, 0, stream>>>(
        hg, pred_W, pred_b, out, N_GRAPHS, OUTD, DIM);
}